// Round 3
// baseline (61.917 us; speedup 1.0000x reference)
//
#include <hip/hip_runtime.h>

#define T_TOKENS 4096
#define F_IN 4096
#define O_OUT 4096
#define SCALE_F 4.0f   // 16 / sqrt(16)

typedef __attribute__((ext_vector_type(8))) short bf16x8;
typedef __attribute__((ext_vector_type(4))) float f32x4;
typedef __attribute__((ext_vector_type(4))) int i32x4;

// ws layout (ushort elements)
#define WBM_E 0          // A packed:  [512][64][8] bf16 frags = 262144
#define WRB_E 262144     // Wr packed: [512][16][8] bf16 frags =  65536 (c0-3 hi, 4-7 lo, 8-15 zero)
#define MIDW_E 327680    // midw [4096][64] bf16 = 262144

__device__ __forceinline__ unsigned short f2bf(float f) {
    unsigned u = __float_as_uint(f);
    return (unsigned short)((u + 0x7fffu + ((u >> 16) & 1u)) >> 16);
}
__device__ __forceinline__ float bf2f(unsigned short h) {
    return __uint_as_float(((unsigned)h) << 16);
}
__device__ __forceinline__ int cvt_pk(float a, float b) {
    int r;
    asm("v_cvt_pk_bf16_f32 %0, %1, %2" : "=v"(r) : "v"(a), "v"(b));
    return r;   // low16 = bf16(a), high16 = bf16(b)
}

// ---------------------------------------------------------------------------
// kprep: pack A and Wr(hi/lo split) into MFMA B-operand frags [k>>3][col][k&7].
// One 8-elem frag per thread; 40960 frags -> 160 blocks.
// ---------------------------------------------------------------------------
__global__ __launch_bounds__(256) void kprep(const float* __restrict__ A,
                                             const float* __restrict__ Wr,
                                             unsigned short* __restrict__ ws) {
    const int f = blockIdx.x * 256 + threadIdx.x;
    if (f < 32768) {                       // A frag: kb = f>>6, c = f&63
        const int kb = f >> 6, c = f & 63;
        const float* src = A + (size_t)c * F_IN + kb * 8;
        float4 a = *(const float4*)src, b = *(const float4*)(src + 4);
        bf16x8 v;
        v[0] = (short)f2bf(a.x); v[1] = (short)f2bf(a.y);
        v[2] = (short)f2bf(a.z); v[3] = (short)f2bf(a.w);
        v[4] = (short)f2bf(b.x); v[5] = (short)f2bf(b.y);
        v[6] = (short)f2bf(b.z); v[7] = (short)f2bf(b.w);
        *(bf16x8*)(ws + WBM_E + (size_t)f * 8) = v;
    } else if (f < 40960) {                // Wr frag
        const int j = f - 32768;
        const int kb = j >> 4, cc = j & 15;
        bf16x8 v = {0,0,0,0,0,0,0,0};
        if (cc < 8) {
            const float* src = Wr + (size_t)(cc & 3) * F_IN + kb * 8;
            float4 a = *(const float4*)src, b = *(const float4*)(src + 4);
            float ff[8] = {a.x, a.y, a.z, a.w, b.x, b.y, b.z, b.w};
            if (cc < 4) {
#pragma unroll
                for (int q = 0; q < 8; ++q) v[q] = (short)f2bf(ff[q]);
            } else {
#pragma unroll
                for (int q = 0; q < 8; ++q) {
                    unsigned short h = f2bf(ff[q]);
                    v[q] = (short)f2bf(ff[q] - bf2f(h));
                }
            }
        }
        *(bf16x8*)(ws + WRB_E + (size_t)j * 8) = v;
    }
}

// ---------------------------------------------------------------------------
// ka_fused: 8 tokens/block, 512 threads (8 waves x 512-K chunks), full K.
// 6 MFMAs/step (4 mid + router hi/lo). LDS reduce -> fp32 top-2 softmax ->
// fold gate*SCALE -> write bf16 midw. Grid 512 (2 blocks/CU).
// MFMA rows 8-15 duplicate rows 0-7 (x rows via lm&7) and are discarded.
// ---------------------------------------------------------------------------
__global__ __launch_bounds__(512) void ka_fused(const float* __restrict__ x,
                                                const unsigned short* __restrict__ wpack,
                                                unsigned short* __restrict__ midw) {
    const int tid = threadIdx.x;
    const int w = tid >> 6, l = tid & 63, lm = l & 15, lk = l >> 4;
    const int tb = (int)blockIdx.x * 8;
    const int kbase = w * 512;

    const bf16x8* wbm8 = (const bf16x8*)(wpack + WBM_E);
    const bf16x8* wrb8 = (const bf16x8*)(wpack + WRB_E);

    f32x4 am0 = {0.f,0.f,0.f,0.f}, am1 = am0, am2 = am0, am3 = am0;
    f32x4 ar0 = am0, ar1 = am0;
    const float* xrow = x + (size_t)(tb + (lm & 7)) * F_IN;

#pragma unroll 4
    for (int s = 0; s < 16; ++s) {
        const int kc = kbase + s * 32 + lk * 8;
        float4 xa = *(const float4*)(xrow + kc);
        float4 xb = *(const float4*)(xrow + kc + 4);
        float f[8] = {xa.x, xa.y, xa.z, xa.w, xb.x, xb.y, xb.z, xb.w};
        i32x4 hi_i, lo_i;
#pragma unroll
        for (int p = 0; p < 4; ++p) {
            float a = f[2*p], b = f[2*p+1];
            int pk = cvt_pk(a, b);
            float la = a - __uint_as_float(((unsigned)pk) << 16);
            float lb = b - __uint_as_float((unsigned)pk & 0xffff0000u);
            hi_i[p] = pk;
            lo_i[p] = cvt_pk(la, lb);
        }
        bf16x8 xhi = __builtin_bit_cast(bf16x8, hi_i);
        bf16x8 xlo = __builtin_bit_cast(bf16x8, lo_i);

        const int kb8 = kc >> 3;
        bf16x8 w0 = wbm8[kb8 * 64 +  0 + lm];
        bf16x8 w1 = wbm8[kb8 * 64 + 16 + lm];
        bf16x8 w2 = wbm8[kb8 * 64 + 32 + lm];
        bf16x8 w3 = wbm8[kb8 * 64 + 48 + lm];
        bf16x8 wr = wrb8[kb8 * 16 + lm];
        am0 = __builtin_amdgcn_mfma_f32_16x16x32_bf16(xhi, w0, am0, 0, 0, 0);
        am1 = __builtin_amdgcn_mfma_f32_16x16x32_bf16(xhi, w1, am1, 0, 0, 0);
        am2 = __builtin_amdgcn_mfma_f32_16x16x32_bf16(xhi, w2, am2, 0, 0, 0);
        am3 = __builtin_amdgcn_mfma_f32_16x16x32_bf16(xhi, w3, am3, 0, 0, 0);
        ar0 = __builtin_amdgcn_mfma_f32_16x16x32_bf16(xhi, wr, ar0, 0, 0, 0);
        ar1 = __builtin_amdgcn_mfma_f32_16x16x32_bf16(xlo, wr, ar1, 0, 0, 0);
    }

    __shared__ float red[8][6][32][4];   // 24 KB (only valid token rows 0-7)
    __shared__ float mids[8][68];
    __shared__ float lgp4[8][16], lgp5[8][16];
    __shared__ float gl[8][4];

    if (l < 32) {
        *(f32x4*)&red[w][0][l][0] = am0;
        *(f32x4*)&red[w][1][l][0] = am1;
        *(f32x4*)&red[w][2][l][0] = am2;
        *(f32x4*)&red[w][3][l][0] = am3;
        *(f32x4*)&red[w][4][l][0] = ar0;
        *(f32x4*)&red[w][5][l][0] = ar1;
    }
    __syncthreads();

#pragma unroll
    for (int it = 0; it < 2; ++it) {
        int j = tid + it * 512;
        if (j < 768) {
            int tile = j >> 7, rem = j & 127, rl = rem >> 2, q = rem & 3;
            float s = 0.f;
#pragma unroll
            for (int ww = 0; ww < 8; ++ww) s += red[ww][tile][rl][q];
            int token = ((rl >> 4) << 2) + q, c = rl & 15;
            if (tile < 4)       mids[token][tile * 16 + c] = s;
            else if (tile == 4) lgp4[token][c] = s;
            else                lgp5[token][c] = s;
        }
    }
    __syncthreads();

    if (tid < 8) {
        float lg[4];
#pragma unroll
        for (int e = 0; e < 4; ++e)
            lg[e] = lgp4[tid][e] + lgp4[tid][4 + e] + lgp5[tid][e] + lgp5[tid][4 + e];
        int i1 = 0; float m1 = lg[0];
#pragma unroll
        for (int e = 1; e < 4; ++e)
            if (lg[e] > m1) { m1 = lg[e]; i1 = e; }
        int i2 = -1; float m2 = 0.f;
#pragma unroll
        for (int e = 0; e < 4; ++e)
            if (e != i1 && (i2 < 0 || lg[e] > m2)) { m2 = lg[e]; i2 = e; }
        float ex = __expf(m2 - m1);
        float inv = 1.f / (1.f + ex);
#pragma unroll
        for (int e = 0; e < 4; ++e) gl[tid][e] = 0.f;
        gl[tid][i1] = inv * SCALE_F;
        gl[tid][i2] = ex * inv * SCALE_F;
    }
    __syncthreads();

    {   // 512 threads, 512 midw values
        int token = tid >> 6, col = tid & 63;
        midw[(size_t)(tb + token) * 64 + col] =
            f2bf(mids[token][col] * gl[token][col >> 4]);
    }
}

// ---------------------------------------------------------------------------
// kb: out[t,o] = midw[t,:] . Bcat[:,o]. B read fp32 directly (r contiguous),
// converted in-reg. 64x64 tile/block, wave per 16 tokens. Grid 4096.
// ---------------------------------------------------------------------------
__global__ __launch_bounds__(256) void kb_mfma(const unsigned short* __restrict__ midw,
                                               const float* __restrict__ B,
                                               float* __restrict__ out) {
    const int tid = threadIdx.x;
    const int w = tid >> 6, l = tid & 63, lm = l & 15, lk = l >> 4;
    const int tb = ((int)blockIdx.x & 63) * 64 + w * 16;
    const int ob = ((int)blockIdx.x >> 6) * 64;
    const bf16x8* m8 = (const bf16x8*)midw;

    f32x4 acc0 = {0.f,0.f,0.f,0.f}, acc1 = acc0, acc2 = acc0, acc3 = acc0;
#pragma unroll
    for (int kk = 0; kk < 2; ++kk) {
        const int kb8 = kk * 4 + lk;          // k8-block 0..7
        const int e = kb8 >> 1, r = (kb8 & 1) * 8;
        bf16x8 ma = m8[(size_t)(tb + lm) * 8 + kb8];
        bf16x8 bf[4];
#pragma unroll
        for (int n = 0; n < 4; ++n) {
            const float* bp = B + ((size_t)e * O_OUT + (ob + n * 16 + lm)) * 16 + r;
            float4 b0 = *(const float4*)bp, b1 = *(const float4*)(bp + 4);
            i32x4 bi;
            bi[0] = cvt_pk(b0.x, b0.y);
            bi[1] = cvt_pk(b0.z, b0.w);
            bi[2] = cvt_pk(b1.x, b1.y);
            bi[3] = cvt_pk(b1.z, b1.w);
            bf[n] = __builtin_bit_cast(bf16x8, bi);
        }
        acc0 = __builtin_amdgcn_mfma_f32_16x16x32_bf16(ma, bf[0], acc0, 0, 0, 0);
        acc1 = __builtin_amdgcn_mfma_f32_16x16x32_bf16(ma, bf[1], acc1, 0, 0, 0);
        acc2 = __builtin_amdgcn_mfma_f32_16x16x32_bf16(ma, bf[2], acc2, 0, 0, 0);
        acc3 = __builtin_amdgcn_mfma_f32_16x16x32_bf16(ma, bf[3], acc3, 0, 0, 0);
    }
#pragma unroll
    for (int q = 0; q < 4; ++q) {
        const size_t row = (size_t)(tb + lk * 4 + q) * O_OUT + ob + lm;
        out[row +  0] = acc0[q];
        out[row + 16] = acc1[q];
        out[row + 32] = acc2[q];
        out[row + 48] = acc3[q];
    }
}

extern "C" void kernel_launch(void* const* d_in, const int* in_sizes, int n_in,
                              void* d_out, int out_size, void* d_ws, size_t ws_size,
                              hipStream_t stream) {
    const float* x  = (const float*)d_in[0];
    const float* A  = (const float*)d_in[1];
    const float* B  = (const float*)d_in[2];
    const float* Wr = (const float*)d_in[3];
    float* out = (float*)d_out;

    unsigned short* wsu = (unsigned short*)d_ws;
    unsigned short* midw = wsu + MIDW_E;

    kprep<<<160, 256, 0, stream>>>(A, Wr, wsu);
    ka_fused<<<512, 512, 0, stream>>>(x, wsu, midw);
    kb_mfma<<<4096, 256, 0, stream>>>(midw, B, out);
}

// Round 4
// 37.956 us; speedup vs baseline: 1.6313x; 1.6313x over previous
//
#include <hip/hip_runtime.h>

#define T_TOKENS 4096
#define F_IN 4096
#define O_OUT 4096
#define SCALE_F 4.0f   // 16 / sqrt(16)

typedef __attribute__((ext_vector_type(8))) short bf16x8;
typedef __attribute__((ext_vector_type(4))) float f32x4;
typedef __attribute__((ext_vector_type(4))) int i32x4;

// ws layout (unsigned short elements)
#define WBM_E 0          // A packed:  [512 kb8][64 col][8]  = 262144
#define WRB_E 262144     // Wr packed: [512 kb8][16 col][8]  =  65536 (c0-3 hi, c4-7 lo, 8-15 zero)
#define BB_E  327680     // B packed:  [8 kb8][4096 o][8]    = 262144

__device__ __forceinline__ unsigned short f2bf(float f) {
    unsigned u = __float_as_uint(f);
    return (unsigned short)((u + 0x7fffu + ((u >> 16) & 1u)) >> 16);
}
__device__ __forceinline__ float bf2f(unsigned short h) {
    return __uint_as_float(((unsigned)h) << 16);
}
__device__ __forceinline__ int cvt_pk(float a, float b) {
    int r;
    asm("v_cvt_pk_bf16_f32 %0, %1, %2" : "=v"(r) : "v"(a), "v"(b));
    return r;   // low16 = bf16(a), high16 = bf16(b)
}

// ---------------------------------------------------------------------------
// kprep: pack A, Wr (hi/lo split), B into MFMA B-operand frags [k>>3][col][k&7].
// One 8-elem frag per thread: 32768 (A) + 8192 (Wr) + 32768 (B) = 73728.
// ---------------------------------------------------------------------------
__global__ __launch_bounds__(256) void kprep(const float* __restrict__ A,
                                             const float* __restrict__ Wr,
                                             const float* __restrict__ B,
                                             unsigned short* __restrict__ ws) {
    const int f = blockIdx.x * 256 + threadIdx.x;
    if (f < 32768) {                       // A frag: kb8 = f>>6, c = f&63
        const int kb8 = f >> 6, c = f & 63;
        const float* src = A + (size_t)c * F_IN + kb8 * 8;
        float4 a = *(const float4*)src, b = *(const float4*)(src + 4);
        i32x4 v;
        v[0] = cvt_pk(a.x, a.y); v[1] = cvt_pk(a.z, a.w);
        v[2] = cvt_pk(b.x, b.y); v[3] = cvt_pk(b.z, b.w);
        *(i32x4*)(ws + WBM_E + (size_t)f * 8) = v;
    } else if (f < 40960) {                // Wr frag (hi/lo, RNE split)
        const int j = f - 32768;
        const int kb8 = j >> 4, cc = j & 15;
        bf16x8 v = {0,0,0,0,0,0,0,0};
        if (cc < 8) {
            const float* src = Wr + (size_t)(cc & 3) * F_IN + kb8 * 8;
            float4 a = *(const float4*)src, b = *(const float4*)(src + 4);
            float ff[8] = {a.x, a.y, a.z, a.w, b.x, b.y, b.z, b.w};
            if (cc < 4) {
#pragma unroll
                for (int q = 0; q < 8; ++q) v[q] = (short)f2bf(ff[q]);
            } else {
#pragma unroll
                for (int q = 0; q < 8; ++q) {
                    unsigned short h = f2bf(ff[q]);
                    v[q] = (short)f2bf(ff[q] - bf2f(h));
                }
            }
        }
        *(bf16x8*)(ws + WRB_E + (size_t)j * 8) = v;
    } else if (f < 73728) {                // B frag: kb8 = j>>12, o = j&4095
        const int j = f - 40960;
        const int kb8 = j >> 12, o = j & 4095;
        // k = kb8*8+ki -> e = kb8>>1, r = (kb8&1)*8 + ki (contiguous in r)
        const float* src = B + ((size_t)(kb8 >> 1) * O_OUT + o) * 16 + (kb8 & 1) * 8;
        float4 a = *(const float4*)src, b = *(const float4*)(src + 4);
        i32x4 v;
        v[0] = cvt_pk(a.x, a.y); v[1] = cvt_pk(a.z, a.w);
        v[2] = cvt_pk(b.x, b.y); v[3] = cvt_pk(b.z, b.w);
        *(i32x4*)(ws + BB_E + (size_t)j * 8) = v;
    }
}

// ---------------------------------------------------------------------------
// kfused: one block = 16 tokens, 512 threads (8 waves x K-chunk 512).
// Phase 1: x @ [A;Wr_hi;Wr_lo] via MFMA (6/step, no duplication).
// LDS 8-way reduce -> fp32 top-2 softmax -> gate*SCALE -> midw bf16 frags in LDS.
// Phase 2: wave w computes out[tb..tb+15][w*512..+512) = midw @ Bcat (K=64).
// Grid 256 (1 block/CU).
// ---------------------------------------------------------------------------
__global__ __launch_bounds__(512) void kfused(const float* __restrict__ x,
                                              const unsigned short* __restrict__ wpack,
                                              float* __restrict__ out) {
    const int tid = threadIdx.x;
    const int w = tid >> 6, l = tid & 63, lm = l & 15, lk = l >> 4;
    const int tb = (int)blockIdx.x * 16;
    const int kbase = w * 512;

    const bf16x8* wbm8 = (const bf16x8*)(wpack + WBM_E);
    const bf16x8* wrb8 = (const bf16x8*)(wpack + WRB_E);
    const bf16x8* bb8  = (const bf16x8*)(wpack + BB_E);

    f32x4 am0 = {0.f,0.f,0.f,0.f}, am1 = am0, am2 = am0, am3 = am0;
    f32x4 ar0 = am0, ar1 = am0;
    const float* xrow = x + (size_t)(tb + lm) * F_IN;

#pragma unroll 4
    for (int s = 0; s < 16; ++s) {
        const int kc = kbase + s * 32 + lk * 8;
        float4 xa = *(const float4*)(xrow + kc);
        float4 xb = *(const float4*)(xrow + kc + 4);
        float f[8] = {xa.x, xa.y, xa.z, xa.w, xb.x, xb.y, xb.z, xb.w};
        i32x4 hi_i, lo_i;
#pragma unroll
        for (int p = 0; p < 4; ++p) {
            float a = f[2*p], b = f[2*p+1];
            int pk = cvt_pk(a, b);
            float la = a - __uint_as_float(((unsigned)pk) << 16);
            float lb = b - __uint_as_float((unsigned)pk & 0xffff0000u);
            hi_i[p] = pk;
            lo_i[p] = cvt_pk(la, lb);
        }
        bf16x8 xhi = __builtin_bit_cast(bf16x8, hi_i);
        bf16x8 xlo = __builtin_bit_cast(bf16x8, lo_i);

        const int kb8 = kc >> 3;
        bf16x8 w0 = wbm8[kb8 * 64 +  0 + lm];
        bf16x8 w1 = wbm8[kb8 * 64 + 16 + lm];
        bf16x8 w2 = wbm8[kb8 * 64 + 32 + lm];
        bf16x8 w3 = wbm8[kb8 * 64 + 48 + lm];
        bf16x8 wr = wrb8[kb8 * 16 + lm];
        am0 = __builtin_amdgcn_mfma_f32_16x16x32_bf16(xhi, w0, am0, 0, 0, 0);
        am1 = __builtin_amdgcn_mfma_f32_16x16x32_bf16(xhi, w1, am1, 0, 0, 0);
        am2 = __builtin_amdgcn_mfma_f32_16x16x32_bf16(xhi, w2, am2, 0, 0, 0);
        am3 = __builtin_amdgcn_mfma_f32_16x16x32_bf16(xhi, w3, am3, 0, 0, 0);
        ar0 = __builtin_amdgcn_mfma_f32_16x16x32_bf16(xhi, wr, ar0, 0, 0, 0);
        ar1 = __builtin_amdgcn_mfma_f32_16x16x32_bf16(xlo, wr, ar1, 0, 0, 0);
    }

    __shared__ float red[8][6][64][4];      // 48 KB
    __shared__ float mids[16][68];
    __shared__ float lgp[2][16][16];
    __shared__ float gl[16][4];
    __shared__ __align__(16) unsigned short mfr[8 * 16 * 8];   // [kb8][token][ki]

    *(f32x4*)&red[w][0][l][0] = am0;
    *(f32x4*)&red[w][1][l][0] = am1;
    *(f32x4*)&red[w][2][l][0] = am2;
    *(f32x4*)&red[w][3][l][0] = am3;
    *(f32x4*)&red[w][4][l][0] = ar0;
    *(f32x4*)&red[w][5][l][0] = ar1;
    __syncthreads();

#pragma unroll
    for (int it = 0; it < 3; ++it) {
        int j = tid + it * 512;
        int tile = j >> 8, rem = j & 255, rl = rem >> 2, q = rem & 3;
        float s = 0.f;
#pragma unroll
        for (int ww = 0; ww < 8; ++ww) s += red[ww][tile][rl][q];
        int token = ((rl >> 4) << 2) + q, c = rl & 15;
        if (tile < 4) mids[token][tile * 16 + c] = s;
        else          lgp[tile - 4][token][c] = s;
    }
    __syncthreads();

    if (tid < 16) {
        float lg[4];
#pragma unroll
        for (int e = 0; e < 4; ++e)
            lg[e] = lgp[0][tid][e] + lgp[0][tid][4 + e]
                  + lgp[1][tid][e] + lgp[1][tid][4 + e];
        int i1 = 0; float m1 = lg[0];
#pragma unroll
        for (int e = 1; e < 4; ++e)
            if (lg[e] > m1) { m1 = lg[e]; i1 = e; }
        int i2 = -1; float m2 = 0.f;
#pragma unroll
        for (int e = 0; e < 4; ++e)
            if (e != i1 && (i2 < 0 || lg[e] > m2)) { m2 = lg[e]; i2 = e; }
        float ex = __expf(m2 - m1);
        float inv = 1.f / (1.f + ex);
#pragma unroll
        for (int e = 0; e < 4; ++e) gl[tid][e] = 0.f;
        gl[tid][i1] = inv * SCALE_F;
        gl[tid][i2] = ex * inv * SCALE_F;
    }
    __syncthreads();

    {   // pack gated mids -> bf16 frags: thread handles token t, k = 2*kp, 2*kp+1
        int t = tid & 15, kp = tid >> 4;      // kp 0..31
        int k0 = kp * 2;
        float g = gl[t][k0 >> 4];             // k0,k0+1 never straddle an expert
        int pk = cvt_pk(mids[t][k0] * g, mids[t][k0 + 1] * g);
        *(int*)&mfr[((k0 >> 3) * 16 + t) * 8 + (k0 & 7)] = pk;
    }
    __syncthreads();

    // ---- Phase 2: out tile [16 tokens][512 cols] per wave ----
    const int ob = w * 512;
    const bf16x8* mf8 = (const bf16x8*)mfr;   // frag index kb8*16 + token
    bf16x8 ma0 = mf8[(0 + lk) * 16 + lm];
    bf16x8 ma1 = mf8[(4 + lk) * 16 + lm];

#pragma unroll 4
    for (int n = 0; n < 32; ++n) {
        const int oc = ob + n * 16;
        bf16x8 b0 = bb8[(size_t)lk * 4096 + oc + lm];
        bf16x8 b1 = bb8[(size_t)(4 + lk) * 4096 + oc + lm];
        f32x4 acc = {0.f,0.f,0.f,0.f};
        acc = __builtin_amdgcn_mfma_f32_16x16x32_bf16(ma0, b0, acc, 0, 0, 0);
        acc = __builtin_amdgcn_mfma_f32_16x16x32_bf16(ma1, b1, acc, 0, 0, 0);
#pragma unroll
        for (int q = 0; q < 4; ++q)
            out[(size_t)(tb + lk * 4 + q) * O_OUT + oc + lm] = acc[q];
    }
}

extern "C" void kernel_launch(void* const* d_in, const int* in_sizes, int n_in,
                              void* d_out, int out_size, void* d_ws, size_t ws_size,
                              hipStream_t stream) {
    const float* x  = (const float*)d_in[0];
    const float* A  = (const float*)d_in[1];
    const float* B  = (const float*)d_in[2];
    const float* Wr = (const float*)d_in[3];
    float* out = (float*)d_out;
    unsigned short* wsu = (unsigned short*)d_ws;

    kprep<<<288, 256, 0, stream>>>(A, Wr, B, wsu);
    kfused<<<256, 512, 0, stream>>>(x, wsu, out);
}